// Round 20
// baseline (815.049 us; speedup 1.0000x reference)
//
#include <hip/hip_runtime.h>

// Problem constants (match reference)
#define SEQ 2048
#define BAT 256
#define KD  64
#define HD  128
#define SBH 67108864u   // SEQ*BAT*HD elements
#define SBHB (SBH * 4u) // bytes

typedef _Float16 half2v  __attribute__((ext_vector_type(2)));  // fdot2 operand type
typedef __fp16   fp16x2  __attribute__((ext_vector_type(2)));  // cvt_pkrtz return type
typedef unsigned uint2v  __attribute__((ext_vector_type(2)));  // permlane32_swap ret

// DPP helpers — ALL direction-proof: 0xB1 = quad_perm(1,0,3,2) = lane^1;
// 0x4E = quad_perm(2,3,0,1) = lane^2; 0x128 = row_ror:8 = lane^8 within a
// 16-lane row (rotation by half the row = involution either direction).
template<int CTRL>
__device__ __forceinline__ float dpp_add(float keep, float send) {
    const int r = __builtin_amdgcn_update_dpp(0, __float_as_int(send),
                                              CTRL, 0xF, 0xF, true);
    return keep + __int_as_float(r);
}

// lane^32 exchange via v_permlane32_swap_b32 (VALU pipe; self-symmetric).
__device__ __forceinline__ float xchg32(float v, int hi_half, int lane) {
#if __has_builtin(__builtin_amdgcn_permlane32_swap)
    uint2v r = __builtin_amdgcn_permlane32_swap(__float_as_uint(v),
                                                __float_as_uint(v),
                                                false, false);
    return __uint_as_float(hi_half ? r.x : r.y);
#else
    return __uint_as_float(__builtin_amdgcn_ds_bpermute(
        ((lane ^ 32) << 2), __float_as_uint(v)));
#endif
}

// Pack two f32 -> f16x2 bits (v_cvt_pkrtz_f16_f32).
__device__ __forceinline__ int PK(float a, float b) {
    fp16x2 p = __builtin_amdgcn_cvt_pkrtz(a, b);
    return __builtin_bit_cast(int, p);
}

// f32 += dot2(f16x2, f16x2) — v_dot2_f32_f16, f32 accumulate.
__device__ __forceinline__ float fdot2(int w, int h, float c) {
#if __has_builtin(__builtin_amdgcn_fdot2)
    return __builtin_amdgcn_fdot2(__builtin_bit_cast(half2v, w),
                                  __builtin_bit_cast(half2v, h), c, false);
#else
    half2v wv = __builtin_bit_cast(half2v, w), hv = __builtin_bit_cast(half2v, h);
    return fmaf((float)wv[1], (float)hv[1], fmaf((float)wv[0], (float)hv[0], c));
#endif
}

// Pin a scalar into a register (loads can't sink past the volatile asm).
#define PIN(x) asm volatile("" : "+v"(x))
#define PIN4(v4) PIN(v4.x); PIN(v4.y); PIN(v4.z); PIN(v4.w)

// LDS-visibility-only barrier: does NOT drain vmcnt (output stores stay in
// flight; the loop has NO VMEM loads, so vmcnt is never waited on).
#define STEP_BARRIER() do {                                   \
    asm volatile("s_waitcnt lgkmcnt(0)" ::: "memory");        \
    __builtin_amdgcn_s_barrier();                             \
    asm volatile("" ::: "memory");                            \
} while (0)

// ---------------------------------------------------------------------------
// Kernel 1: precompute type-dependent tables into d_ws (f32).
//   tabH[ty][r] = sum_k embed_W[ty][k]*W_ih[r][k] + b_ih[r] + b_hh[r]
//   tabD[ty][r] = sum_k embed_W[ty][k]*dec_W[r][k] + dec_b[r]
// ---------------------------------------------------------------------------
__global__ __launch_bounds__(128) void precompute_tables(
    const float* __restrict__ embed_W, const float* __restrict__ W_ih,
    const float* __restrict__ b_ih,    const float* __restrict__ b_hh,
    const float* __restrict__ dec_W,   const float* __restrict__ dec_b,
    float* __restrict__ tabH, float* __restrict__ tabD)
{
    __shared__ float x[KD];
    const int ty = blockIdx.x;   // 0..64 (row 64 = padding, embed row is zero)
    const int r  = threadIdx.x;  // 0..127
    if (r < KD) x[r] = embed_W[ty * KD + r];
    __syncthreads();
    float ah = 0.f, ad = 0.f;
#pragma unroll
    for (int k = 0; k < KD; ++k) {
        const float xv = x[k];
        ah += xv * W_ih[r * KD + k];
        ad += xv * dec_W[r * (KD + HD) + k];
    }
    tabH[ty * HD + r] = ah + b_ih[r] + b_hh[r];
    tabD[ty * HD + r] = ad + dec_b[r];
}

// ---------------------------------------------------------------------------
// Kernel 2: persistent per-batch-element recurrence. One WG per batch elem,
// 256 threads = 4 waves (r19 structure, best 799us). Round-20 micro-combo:
//  1. tab folded into accumulator a0 init (slot 0 = own row) — removes the
//     tail add from the serial chain.
//  2. Balanced stores: b5=0 lanes {hidden store + LDS h-write}, b5=1 lanes
//     {decay + hidden_ti stores} (b5=1 lanes hold hnew via the exchange).
//  3. Byte-offset store addressing (one v_add per step).
// Lane bits: b0,b1,b3 = chunk bits (xor-resolved row bits via select-free
// slot-xor weights); b2,b4 static row bits; b5 = type. G = wave*4 + b4*2+b2.
// chunk = b0|b1<<1|b3<<2; row = 8G + 4b0+2b1+b3. 64 fdot2/lane.
// Tables in LDS f16 -> loop has zero VMEM loads. One lgkm-only barrier/step.
// ---------------------------------------------------------------------------
__global__ __launch_bounds__(256, 1) void hawkes_rnn(
    const float* __restrict__ dt_g,  const float* __restrict__ h0,
    const float* __restrict__ W_hh,  const float* __restrict__ dec_W,
    const int*   __restrict__ seq_types,
    const float* __restrict__ tabH,  const float* __restrict__ tabD,
    float* __restrict__ out)
{
    __shared__ __align__(16) _Float16 h16[2][HD];       //    512 B
    __shared__ __align__(8) int2 dtty[SEQ + 2];         // 16,400 B {dt, ty}
    __shared__ _Float16 tabLH[(KD + 1) * HD];           // 16,640 B
    __shared__ _Float16 tabLD[(KD + 1) * HD];           // 16,640 B (tot ~50 KB)

    const int b    = blockIdx.x;
    const int tid  = threadIdx.x;
    const int lane = tid & 63;
    const int b0 = lane & 1, b1 = (lane >> 1) & 1;
    const int b2 = (lane >> 2) & 1, b3 = (lane >> 3) & 1;
    const int b4 = (lane >> 4) & 1, b5 = (lane >> 5) & 1;
    const int G     = (tid >> 6) * 4 + b4 * 2 + b2;       // row octet 0..15
    const int r0_   = 4 * b0 + 2 * b1 + b3;               // xor-base within octet
    const int row   = 8 * G + r0_;                        // row this lane owns
    const int chunk = b0 | (b1 << 1) | (b3 << 2);         // h-col block /16

    // Stage packed {dt, ty} pairs + both bias tables (f32 -> f16) + h0.
    for (int t = tid; t < SEQ; t += 256) {
        dtty[t] = make_int2(__float_as_int(dt_g[(size_t)t * BAT + b]),
                            seq_types[(size_t)t * BAT + b]);
    }
    if (tid < 2) dtty[SEQ + tid] = make_int2(0, 0);   // prefetch-pad
    for (int i = tid; i < (KD + 1) * HD; i += 256) {
        tabLH[i] = (_Float16)tabH[i];
        tabLD[i] = (_Float16)tabD[i];
    }
    if (tid < HD) h16[0][tid] = (_Float16)h0[b * HD + tid];

    // Load + convert weight slots: slot s = row 8G + (r0_^s), cols
    // 16*chunk..+15 of this lane's type matrix -> 2 int4 (8 f16x2) per slot.
    const size_t rstr = b5 ? (size_t)(KD + HD) : (size_t)HD;
    const float* mat = (b5 ? (dec_W + KD) : W_hh);
#define LWROW(DA, DB, S) { \
    const float* _p = mat + (size_t)(8 * G + (r0_ ^ (S))) * rstr + chunk * 16; \
    const float4 _a = *reinterpret_cast<const float4*>(_p);        \
    const float4 _b = *reinterpret_cast<const float4*>(_p + 4);    \
    const float4 _c = *reinterpret_cast<const float4*>(_p + 8);    \
    const float4 _d = *reinterpret_cast<const float4*>(_p + 12);   \
    DA = make_int4(PK(_a.x,_a.y), PK(_a.z,_a.w), PK(_b.x,_b.y), PK(_b.z,_b.w)); \
    DB = make_int4(PK(_c.x,_c.y), PK(_c.z,_c.w), PK(_d.x,_d.y), PK(_d.z,_d.w)); }
    int4 w0a,w0b,w1a,w1b,w2a,w2b,w3a,w3b,w4a,w4b,w5a,w5b,w6a,w6b,w7a,w7b;
    LWROW(w0a,w0b, 0)  LWROW(w1a,w1b, 1)
    LWROW(w2a,w2b, 2)  LWROW(w3a,w3b, 3)
    LWROW(w4a,w4b, 4)  LWROW(w5a,w5b, 5)
    LWROW(w6a,w6b, 6)  LWROW(w7a,w7b, 7)
#undef LWROW
    PIN4(w0a); PIN4(w0b); PIN4(w1a); PIN4(w1b);
    PIN4(w2a); PIN4(w2b); PIN4(w3a); PIN4(w3b);
    PIN4(w4a); PIN4(w4b); PIN4(w5a); PIN4(w5b);
    PIN4(w6a); PIN4(w6b); PIN4(w7a); PIN4(w7b);

    const _Float16* tabp = (b5 ? tabLD : tabLH) + row;

    // Byte-offset store bases. b5=0 lanes store hidden at plane 0; b5=1 lanes
    // store decay at plane 1 and hidden_ti at plane 2 (= first base + SBHB).
    char* outc = (char*)out;
    unsigned offb = (unsigned)(b * HD + row) * 4u + (b5 ? SBHB : 0u);

    __syncthreads();   // staging visible

    // Pipelines: (dt,ty) pair and LDS tab read, 2 steps ahead.
    int2 pr_cur = dtty[0];
    int2 pr_nxt = dtty[1];
    float tab_cur = (float)tabp[pr_cur.y * HD];
    float tab_nxt = (float)tabp[pr_nxt.y * HD];

    float stv_c = 0.f, hnew_c = 0.f;   // carried store values (prev step)

#define DOT16(A, WA, WB) \
    A = fdot2(WA.x, hv0.x, A); A = fdot2(WA.y, hv0.y, A); \
    A = fdot2(WA.z, hv0.z, A); A = fdot2(WA.w, hv0.w, A); \
    A = fdot2(WB.x, hv1.x, A); A = fdot2(WB.y, hv1.y, A); \
    A = fdot2(WB.z, hv1.z, A); A = fdot2(WB.w, hv1.w, A);

#define STEP(P, TT, DOST) { \
    /* h chunk reads FIRST (latency overlaps the carried stores below) */ \
    const int4 hv0 = *reinterpret_cast<const int4*>(&h16[P][chunk * 16]); \
    const int4 hv1 = *reinterpret_cast<const int4*>(&h16[P][chunk * 16 + 8]); \
    if (DOST) {                         /* stores of the PREVIOUS step */ \
        *(float*)(outc + offb) = stv_c; \
        if (b5) *(float*)(outc + offb + SBHB) = hnew_c; \
        offb += BAT * HD * 4u; \
    } \
    const int2 pr_pf = dtty[(TT) + 2];               /* one b64 read */ \
    const float tab_pf = (float)tabp[pr_pf.y * HD];  /* LDS read, use TT+2 */ \
    const float dtv = __int_as_float(pr_cur.x); \
    float a0 = tab_cur;                  /* tab folded into acc init */ \
    float a1 = 0.f, a2 = 0.f, a3 = 0.f; \
    float a4 = 0.f, a5 = 0.f, a6 = 0.f, a7 = 0.f; \
    DOT16(a0, w0a, w0b)  DOT16(a1, w1a, w1b) \
    DOT16(a2, w2a, w2b)  DOT16(a3, w3a, w3b) \
    DOT16(a4, w4a, w4b)  DOT16(a5, w5a, w5b) \
    DOT16(a6, w6a, w6b)  DOT16(a7, w7a, w7b) \
    /* select-free butterfly (slot s = row 8G + (r0_^s)) */ \
    const float t0 = dpp_add<0xB1>(a0, a4); \
    const float t1 = dpp_add<0xB1>(a1, a5); \
    const float t2 = dpp_add<0xB1>(a2, a6); \
    const float t3 = dpp_add<0xB1>(a3, a7); \
    const float u0 = dpp_add<0x4E>(t0, t2); \
    const float u1 = dpp_add<0x4E>(t1, t3); \
    const float sv = dpp_add<0x128>(u0, u1); \
    /* activations (branchless; all lanes both paths) */ \
    const float e2 = __expf(2.f * sv); \
    const float vh = 1.f - __fdividef(2.f, e2 + 1.f);            /* tanh */ \
    const float z  = 10.f * sv; \
    const float em = __expf(-fabsf(z)); \
    const float sp = 0.1f * (fmaxf(z, 0.f) + __logf(1.f + em));  /* softplus10 */ \
    const float vd = __expf(-sp * dtv); \
    const float v  = b5 ? vd : vh; \
    /* type exchange lane^32: permlane32_swap (VALU, self-symmetric) */ \
    const float cross = xchg32(v, b5, lane); \
    const float hnew  = v * cross; \
    if (b5 == 0) h16[(P) ^ 1][row] = (_Float16)hnew;   /* pre-barrier */ \
    stv_c  = b5 ? sp : v; \
    hnew_c = hnew; \
    pr_cur = pr_nxt;   pr_nxt = pr_pf; \
    tab_cur = tab_nxt; tab_nxt = tab_pf; \
    STEP_BARRIER(); \
}

    STEP(0, 0, 0)          // step 0: nothing carried yet
    STEP(1, 1, 1)          // step 1: stores step 0
    for (int t = 2; t < SEQ; t += 2) {
        STEP(0, t, 1)      // stores t-1
        STEP(1, t + 1, 1)  // stores t
    }
    // final stores: step SEQ-1 results
    *(float*)(outc + offb) = stv_c;
    if (b5) *(float*)(outc + offb + SBHB) = hnew_c;
#undef STEP
#undef DOT16
}

extern "C" void kernel_launch(void* const* d_in, const int* in_sizes, int n_in,
                              void* d_out, int out_size, void* d_ws, size_t ws_size,
                              hipStream_t stream) {
    const float* dt        = (const float*)d_in[0];
    const float* h0        = (const float*)d_in[1];
    const float* embed_W   = (const float*)d_in[2];
    const float* W_ih      = (const float*)d_in[3];
    const float* b_ih      = (const float*)d_in[4];
    const float* W_hh      = (const float*)d_in[5];
    const float* b_hh      = (const float*)d_in[6];
    const float* dec_W     = (const float*)d_in[7];
    const float* dec_b     = (const float*)d_in[8];
    const int*   seq_types = (const int*)  d_in[9];
    float* out  = (float*)d_out;

    float* tabHw = (float*)d_ws;                 // [65][128]
    float* tabDw = tabHw + (KD + 1) * HD;        // [65][128]

    precompute_tables<<<KD + 1, 128, 0, stream>>>(embed_W, W_ih, b_ih, b_hh,
                                                  dec_W, dec_b, tabHw, tabDw);
    hawkes_rnn<<<BAT, 256, 0, stream>>>(dt, h0, W_hh, dec_W, seq_types,
                                        tabHw, tabDw, out);
}

// Round 21
// 798.265 us; speedup vs baseline: 1.0210x; 1.0210x over previous
//
#include <hip/hip_runtime.h>

// Problem constants (match reference)
#define SEQ 2048
#define BAT 256
#define KD  64
#define HD  128
#define SBH 67108864u   // SEQ*BAT*HD

typedef _Float16 half2v  __attribute__((ext_vector_type(2)));  // fdot2 operand type
typedef __fp16   fp16x2  __attribute__((ext_vector_type(2)));  // cvt_pkrtz return type
typedef unsigned uint2v  __attribute__((ext_vector_type(2)));  // permlane32_swap ret

// DPP helpers — ALL direction-proof: 0xB1 = quad_perm(1,0,3,2) = lane^1;
// 0x4E = quad_perm(2,3,0,1) = lane^2; 0x128 = row_ror:8 = lane^8 within a
// 16-lane row (rotation by half the row = involution either direction).
template<int CTRL>
__device__ __forceinline__ float dpp_add(float keep, float send) {
    const int r = __builtin_amdgcn_update_dpp(0, __float_as_int(send),
                                              CTRL, 0xF, 0xF, true);
    return keep + __int_as_float(r);
}

// lane^32 exchange via v_permlane32_swap_b32 (VALU pipe; self-symmetric).
__device__ __forceinline__ float xchg32(float v, int hi_half, int lane) {
#if __has_builtin(__builtin_amdgcn_permlane32_swap)
    uint2v r = __builtin_amdgcn_permlane32_swap(__float_as_uint(v),
                                                __float_as_uint(v),
                                                false, false);
    return __uint_as_float(hi_half ? r.x : r.y);
#else
    return __uint_as_float(__builtin_amdgcn_ds_bpermute(
        ((lane ^ 32) << 2), __float_as_uint(v)));
#endif
}

// Pack two f32 -> f16x2 bits (v_cvt_pkrtz_f16_f32).
__device__ __forceinline__ int PK(float a, float b) {
    fp16x2 p = __builtin_amdgcn_cvt_pkrtz(a, b);
    return __builtin_bit_cast(int, p);
}

// f32 += dot2(f16x2, f16x2) — v_dot2_f32_f16, f32 accumulate.
__device__ __forceinline__ float fdot2(int w, int h, float c) {
#if __has_builtin(__builtin_amdgcn_fdot2)
    return __builtin_amdgcn_fdot2(__builtin_bit_cast(half2v, w),
                                  __builtin_bit_cast(half2v, h), c, false);
#else
    half2v wv = __builtin_bit_cast(half2v, w), hv = __builtin_bit_cast(half2v, h);
    return fmaf((float)wv[1], (float)hv[1], fmaf((float)wv[0], (float)hv[0], c));
#endif
}

// Pin a scalar into a register (loads can't sink past the volatile asm).
#define PIN(x) asm volatile("" : "+v"(x))
#define PIN4(v4) PIN(v4.x); PIN(v4.y); PIN(v4.z); PIN(v4.w)

// LDS-visibility-only barrier: does NOT drain vmcnt (output stores stay in
// flight; the loop has NO VMEM loads, so vmcnt is never waited on).
#define STEP_BARRIER() do {                                   \
    asm volatile("s_waitcnt lgkmcnt(0)" ::: "memory");        \
    __builtin_amdgcn_s_barrier();                             \
    asm volatile("" ::: "memory");                            \
} while (0)

// ---------------------------------------------------------------------------
// Kernel 1: precompute type-dependent tables into d_ws (f32).
//   tabH[ty][r] = sum_k embed_W[ty][k]*W_ih[r][k] + b_ih[r] + b_hh[r]
//   tabD[ty][r] = sum_k embed_W[ty][k]*dec_W[r][k] + dec_b[r]
// ---------------------------------------------------------------------------
__global__ __launch_bounds__(128) void precompute_tables(
    const float* __restrict__ embed_W, const float* __restrict__ W_ih,
    const float* __restrict__ b_ih,    const float* __restrict__ b_hh,
    const float* __restrict__ dec_W,   const float* __restrict__ dec_b,
    float* __restrict__ tabH, float* __restrict__ tabD)
{
    __shared__ float x[KD];
    const int ty = blockIdx.x;   // 0..64 (row 64 = padding, embed row is zero)
    const int r  = threadIdx.x;  // 0..127
    if (r < KD) x[r] = embed_W[ty * KD + r];
    __syncthreads();
    float ah = 0.f, ad = 0.f;
#pragma unroll
    for (int k = 0; k < KD; ++k) {
        const float xv = x[k];
        ah += xv * W_ih[r * KD + k];
        ad += xv * dec_W[r * (KD + HD) + k];
    }
    tabH[ty * HD + r] = ah + b_ih[r] + b_hh[r];
    tabD[ty * HD + r] = ad + dec_b[r];
}

// ---------------------------------------------------------------------------
// Kernel 2: persistent per-batch-element recurrence. One WG per batch elem,
// 256 threads = 4 waves. BEST VERIFIED VARIANT (round 19, 799 us):
//  - select-free xor-slot butterfly (slot s = row 8G + (r0^s)): all three
//    reduction stages are plain dpp_add, zero cndmask.
//  - stores carried in regs, issued at the TOP of the next step (overlap the
//    h ds_read latency; never in the pre-barrier chain).
//  - bias tables in LDS f16 -> the loop has ZERO VMEM loads; output stores
//    are fire-and-forget (vmcnt never waited).
//  - lgkm-only barrier (no vmcnt drain), 2x unrolled double-buffered h.
// Lane bits: b0,b1,b3 = chunk bits (xor-resolved row bits); b2,b4 static row
// bits; b5 = type (0=hidden, 1=decay). G = wave*4 + b4*2 + b2.
// chunk = b0|b1<<1|b3<<2; row = 8G + 4b0+2b1+b3. 64 fdot2/lane/step.
// Floor analysis (r8-r20): step = 937 cyc = ~540 issue (near 256-cyc/CU dot
// floor + epilogue) + ~355 serial-chain idle (invariant across wave counts).
// ---------------------------------------------------------------------------
__global__ __launch_bounds__(256, 1) void hawkes_rnn(
    const float* __restrict__ dt_g,  const float* __restrict__ h0,
    const float* __restrict__ W_hh,  const float* __restrict__ dec_W,
    const int*   __restrict__ seq_types,
    const float* __restrict__ tabH,  const float* __restrict__ tabD,
    float* __restrict__ out)
{
    __shared__ __align__(16) _Float16 h16[2][HD];       //    512 B
    __shared__ __align__(8) int2 dtty[SEQ + 2];         // 16,400 B {dt, ty}
    __shared__ _Float16 tabLH[(KD + 1) * HD];           // 16,640 B
    __shared__ _Float16 tabLD[(KD + 1) * HD];           // 16,640 B (tot ~50 KB)

    const int b    = blockIdx.x;
    const int tid  = threadIdx.x;
    const int lane = tid & 63;
    const int b0 = lane & 1, b1 = (lane >> 1) & 1;
    const int b2 = (lane >> 2) & 1, b3 = (lane >> 3) & 1;
    const int b4 = (lane >> 4) & 1, b5 = (lane >> 5) & 1;
    const int G     = (tid >> 6) * 4 + b4 * 2 + b2;       // row octet 0..15
    const int r0_   = 4 * b0 + 2 * b1 + b3;               // xor-base within octet
    const int row   = 8 * G + r0_;                        // row this lane owns
    const int chunk = b0 | (b1 << 1) | (b3 << 2);         // h-col block /16

    // Stage packed {dt, ty} pairs + both bias tables (f32 -> f16) + h0.
    for (int t = tid; t < SEQ; t += 256) {
        dtty[t] = make_int2(__float_as_int(dt_g[(size_t)t * BAT + b]),
                            seq_types[(size_t)t * BAT + b]);
    }
    if (tid < 2) dtty[SEQ + tid] = make_int2(0, 0);   // prefetch-pad
    for (int i = tid; i < (KD + 1) * HD; i += 256) {
        tabLH[i] = (_Float16)tabH[i];
        tabLD[i] = (_Float16)tabD[i];
    }
    if (tid < HD) h16[0][tid] = (_Float16)h0[b * HD + tid];

    // Load + convert weight slots: slot s = row 8G + (r0_^s), cols
    // 16*chunk..+15 of this lane's type matrix -> 2 int4 (8 f16x2) per slot.
    const size_t rstr = b5 ? (size_t)(KD + HD) : (size_t)HD;
    const float* mat = (b5 ? (dec_W + KD) : W_hh);
#define LWROW(DA, DB, S) { \
    const float* _p = mat + (size_t)(8 * G + (r0_ ^ (S))) * rstr + chunk * 16; \
    const float4 _a = *reinterpret_cast<const float4*>(_p);        \
    const float4 _b = *reinterpret_cast<const float4*>(_p + 4);    \
    const float4 _c = *reinterpret_cast<const float4*>(_p + 8);    \
    const float4 _d = *reinterpret_cast<const float4*>(_p + 12);   \
    DA = make_int4(PK(_a.x,_a.y), PK(_a.z,_a.w), PK(_b.x,_b.y), PK(_b.z,_b.w)); \
    DB = make_int4(PK(_c.x,_c.y), PK(_c.z,_c.w), PK(_d.x,_d.y), PK(_d.z,_d.w)); }
    int4 w0a,w0b,w1a,w1b,w2a,w2b,w3a,w3b,w4a,w4b,w5a,w5b,w6a,w6b,w7a,w7b;
    LWROW(w0a,w0b, 0)  LWROW(w1a,w1b, 1)
    LWROW(w2a,w2b, 2)  LWROW(w3a,w3b, 3)
    LWROW(w4a,w4b, 4)  LWROW(w5a,w5b, 5)
    LWROW(w6a,w6b, 6)  LWROW(w7a,w7b, 7)
#undef LWROW
    PIN4(w0a); PIN4(w0b); PIN4(w1a); PIN4(w1b);
    PIN4(w2a); PIN4(w2b); PIN4(w3a); PIN4(w3b);
    PIN4(w4a); PIN4(w4b); PIN4(w5a); PIN4(w5b);
    PIN4(w6a); PIN4(w6b); PIN4(w7a); PIN4(w7b);

    const _Float16* tabp = (b5 ? tabLD : tabLH) + row;

    // Running element offset for this lane's store task (advances per store).
    unsigned off = (unsigned)(b * HD + row);

    __syncthreads();   // staging visible

    // Pipelines: (dt,ty) pair and LDS tab read, 2 steps ahead.
    int2 pr_cur = dtty[0];
    int2 pr_nxt = dtty[1];
    float tab_cur = (float)tabp[pr_cur.y * HD];
    float tab_nxt = (float)tabp[pr_nxt.y * HD];

    float stv_c = 0.f, hnew_c = 0.f;   // carried store values (prev step)

#define DOT16(A, WA, WB) \
    A = fdot2(WA.x, hv0.x, A); A = fdot2(WA.y, hv0.y, A); \
    A = fdot2(WA.z, hv0.z, A); A = fdot2(WA.w, hv0.w, A); \
    A = fdot2(WB.x, hv1.x, A); A = fdot2(WB.y, hv1.y, A); \
    A = fdot2(WB.z, hv1.z, A); A = fdot2(WB.w, hv1.w, A);

#define STEP(P, TT, DOST) { \
    /* h chunk reads FIRST (latency overlaps the carried stores below) */ \
    const int4 hv0 = *reinterpret_cast<const int4*>(&h16[P][chunk * 16]); \
    const int4 hv1 = *reinterpret_cast<const int4*>(&h16[P][chunk * 16 + 8]); \
    if (DOST) {                         /* stores of the PREVIOUS step */ \
        if (b5 == 0) { out[off] = stv_c; out[off + 2u * SBH] = hnew_c; } \
        else         { out[off + SBH] = stv_c; } \
        off += BAT * HD; \
    } \
    const int2 pr_pf = dtty[(TT) + 2];               /* one b64 read */ \
    const float tab_pf = (float)tabp[pr_pf.y * HD];  /* LDS read, use TT+2 */ \
    const float dtv = __int_as_float(pr_cur.x); \
    float a0 = 0.f, a1 = 0.f, a2 = 0.f, a3 = 0.f; \
    float a4 = 0.f, a5 = 0.f, a6 = 0.f, a7 = 0.f; \
    DOT16(a0, w0a, w0b)  DOT16(a1, w1a, w1b) \
    DOT16(a2, w2a, w2b)  DOT16(a3, w3a, w3b) \
    DOT16(a4, w4a, w4b)  DOT16(a5, w5a, w5b) \
    DOT16(a6, w6a, w6b)  DOT16(a7, w7a, w7b) \
    /* select-free butterfly: partner's slot holds the same row by */ \
    /* construction (slot s = row 8G + (r0_^s)) */ \
    const float t0 = dpp_add<0xB1>(a0, a4); \
    const float t1 = dpp_add<0xB1>(a1, a5); \
    const float t2 = dpp_add<0xB1>(a2, a6); \
    const float t3 = dpp_add<0xB1>(a3, a7); \
    const float u0 = dpp_add<0x4E>(t0, t2); \
    const float u1 = dpp_add<0x4E>(t1, t3); \
    const float sv = dpp_add<0x128>(u0, u1) + tab_cur; \
    /* activations (branchless; all lanes both paths) */ \
    const float e2 = __expf(2.f * sv); \
    const float vh = 1.f - __fdividef(2.f, e2 + 1.f);            /* tanh */ \
    const float z  = 10.f * sv; \
    const float em = __expf(-fabsf(z)); \
    const float sp = 0.1f * (fmaxf(z, 0.f) + __logf(1.f + em));  /* softplus10 */ \
    const float vd = __expf(-sp * dtv); \
    const float v  = b5 ? vd : vh; \
    /* type exchange lane^32: permlane32_swap (VALU, self-symmetric) */ \
    const float cross = xchg32(v, b5, lane); \
    const float hnew  = v * cross; \
    if (b5 == 0) h16[(P) ^ 1][row] = (_Float16)hnew;   /* pre-barrier */ \
    stv_c  = b5 ? sp : v; \
    hnew_c = hnew; \
    pr_cur = pr_nxt;   pr_nxt = pr_pf; \
    tab_cur = tab_nxt; tab_nxt = tab_pf; \
    STEP_BARRIER(); \
}

    STEP(0, 0, 0)          // step 0: nothing carried yet
    STEP(1, 1, 1)          // step 1: stores step 0
    for (int t = 2; t < SEQ; t += 2) {
        STEP(0, t, 1)      // stores t-1
        STEP(1, t + 1, 1)  // stores t
    }
    // final stores: step SEQ-1 results
    if (b5 == 0) { out[off] = stv_c; out[off + 2u * SBH] = hnew_c; }
    else         { out[off + SBH] = stv_c; }
#undef STEP
#undef DOT16
}

extern "C" void kernel_launch(void* const* d_in, const int* in_sizes, int n_in,
                              void* d_out, int out_size, void* d_ws, size_t ws_size,
                              hipStream_t stream) {
    const float* dt        = (const float*)d_in[0];
    const float* h0        = (const float*)d_in[1];
    const float* embed_W   = (const float*)d_in[2];
    const float* W_ih      = (const float*)d_in[3];
    const float* b_ih      = (const float*)d_in[4];
    const float* W_hh      = (const float*)d_in[5];
    const float* b_hh      = (const float*)d_in[6];
    const float* dec_W     = (const float*)d_in[7];
    const float* dec_b     = (const float*)d_in[8];
    const int*   seq_types = (const int*)  d_in[9];
    float* out  = (float*)d_out;

    float* tabHw = (float*)d_ws;                 // [65][128]
    float* tabDw = tabHw + (KD + 1) * HD;        // [65][128]

    precompute_tables<<<KD + 1, 128, 0, stream>>>(embed_W, W_ih, b_ih, b_hh,
                                                  dec_W, dec_b, tabHw, tabDw);
    hawkes_rnn<<<BAT, 256, 0, stream>>>(dt, h0, W_hh, dec_W, seq_types,
                                        tabHw, tabDw, out);
}